// Round 10
// baseline (291.844 us; speedup 1.0000x reference)
//
#include <hip/hip_runtime.h>
#include <hip/hip_bf16.h>
#include <math.h>

#define NN   4096
#define FEAT 512
#define DIM  64
#define KC   100
#define LL   3

// ---- workspace layout (float offsets). Total ~20MB.
#define OFF_DFLAT   0                          // [4096] adj row sums (atomic)
#define OFF_CHSUM   4096                       // [64]
#define OFF_CHSQ    4160                       // [64]
#define ZERO_FLOATS 4224                       // zeroed by xwk blocks 0..16
#define OFF_XW      4224                       // [4096*64] fp32
#define OFF_YPART   (OFF_XW + NN*DIM)          // 8 slices fp32
#define OFF_GPART   (OFF_YPART + 8*NN*DIM)     // [64*128*192]
#define OFF_Y0      (OFF_GPART + 64*128*192)   // [4096*64]
#define OFF_TBUF    (OFF_Y0 + NN*DIM)          // [101*64]
#define OFF_QKV     (OFF_TBUF + 101*DIM)       // [101*192]
#define OFF_SS      (OFF_QKV + 101*192)        // [100*100]
#define OFF_DENP    (OFF_SS + KC*KC)           // [1024]
#define OFF_NUMP    (OFF_DENP + 1024)          // [2048]
#define OFF_SB16    (OFF_NUMP + 2048)          // [4096*128] bf16
#define OFF_STB16   (OFF_SB16 + NN*128/2)      // [128*4096] bf16
#define OFF_YNT16   (OFF_STB16 + NN*128/2)     // [64*4096] bf16
#define OFF_XWT16   (OFF_YNT16 + NN*DIM/2)     // [64*4096] bf16

typedef __attribute__((ext_vector_type(8))) short bfrag;   // 8 bf16 (4 VGPRs)
typedef __attribute__((ext_vector_type(4))) float ffrag;   // 4 fp32 acc

__device__ __forceinline__ unsigned short f2bf(float f) {
    union { float f; unsigned u; } v; v.f = f;
    return (unsigned short)((v.u + 0x7FFFu + ((v.u >> 16) & 1u)) >> 16);
}
__device__ __forceinline__ float bf2f(unsigned short u) {
    union { unsigned u; float f; } v; v.u = (unsigned)u << 16; return v.f;
}
__device__ __forceinline__ unsigned int pk2(float a, float b) {
    __hip_bfloat162 h = __float22bfloat162_rn(make_float2(a, b));
    return *(unsigned int*)&h;
}

__device__ __forceinline__ float wsum(float v) {
#pragma unroll
    for (int o = 32; o > 0; o >>= 1) v += __shfl_xor(v, o, 64);
    return v;
}
__device__ __forceinline__ float wmax(float v) {
#pragma unroll
    for (int o = 32; o > 0; o >>= 1) v = fmaxf(v, __shfl_xor(v, o, 64));
    return v;
}
__device__ __forceinline__ float hsum32(float v) {
#pragma unroll
    for (int o = 16; o > 0; o >>= 1) v += __shfl_xor(v, o, 64);
    return v;
}
__device__ __forceinline__ float hmax32(float v) {
#pragma unroll
    for (int o = 16; o > 0; o >>= 1) v = fmaxf(v, __shfl_xor(v, o, 64));
    return v;
}

// xw = x @ conv_w (fp32, K=512 full) -> xw fp32 + xwT bf16. grid 256 x 16 rows.
// Also zero-inits ws[0..ZERO_FLOATS) from blocks 0..16.
__global__ __launch_bounds__(256) void xwk(const float* __restrict__ x,
                                           const float* __restrict__ B,
                                           float* __restrict__ xw,
                                           unsigned short* __restrict__ xwT,
                                           float* __restrict__ zws) {
    __shared__ float a_sh[16 * 68];
    __shared__ float b_sh[64 * 68];
    __shared__ unsigned short tl[64 * 17];
    const int t = threadIdx.x, rb = blockIdx.x;
    if (rb < 17) {
        const int zi = rb * 256 + t;
        if (zi < ZERO_FLOATS) zws[zi] = 0.f;
    }
    const int r = t >> 4, cg = (t & 15) * 4;
    float4 acc = make_float4(0.f, 0.f, 0.f, 0.f);
    for (int kt = 0; kt < FEAT; kt += 64) {
        *(float4*)&a_sh[(t >> 4) * 68 + (t & 15) * 4] =
            *(const float4*)(x + (size_t)(rb * 16 + (t >> 4)) * FEAT + kt + (t & 15) * 4);
#pragma unroll
        for (int p = 0; p < 4; ++p) {
            const int idx = t + 256 * p;
            const int kr = idx >> 4, c4 = (idx & 15) * 4;
            *(float4*)&b_sh[kr * 68 + c4] = *(const float4*)(B + (size_t)(kt + kr) * DIM + c4);
        }
        __syncthreads();
#pragma unroll 8
        for (int k = 0; k < 64; ++k) {
            const float av = a_sh[r * 68 + k];
            const float4 bv = *(float4*)&b_sh[k * 68 + cg];
            acc.x += av * bv.x; acc.y += av * bv.y;
            acc.z += av * bv.z; acc.w += av * bv.w;
        }
        __syncthreads();
    }
    *(float4*)&xw[(size_t)(rb * 16 + r) * DIM + cg] = acc;
    tl[(cg + 0) * 17 + r] = f2bf(acc.x);
    tl[(cg + 1) * 17 + r] = f2bf(acc.y);
    tl[(cg + 2) * 17 + r] = f2bf(acc.z);
    tl[(cg + 3) * 17 + r] = f2bf(acc.w);
    __syncthreads();
    const int d = t >> 2, c = (t & 3) * 4;
    ushort4 o;
    o.x = tl[d * 17 + c + 0]; o.y = tl[d * 17 + c + 1];
    o.z = tl[d * 17 + c + 2]; o.w = tl[d * 17 + c + 3];
    *(ushort4*)(xwT + (size_t)d * NN + rb * 16 + c) = o;
}

// ypart[ksl] = adj_bf16 @ xwT^T, 16-row tiles, grid (256, 8). 8 blocks/CU.
__global__ __launch_bounds__(256) void gemmA(const float* __restrict__ adj,
                                             const unsigned short* __restrict__ xwT,
                                             float* __restrict__ ypart,
                                             float* __restrict__ dflat) {
    __shared__ __align__(16) unsigned short a_sh[16 * 72];
    __shared__ __align__(16) unsigned short b_sh[64 * 72];
    const int t  = threadIdx.x;
    const int rb = blockIdx.x;                 // 0..255
    const int k0 = blockIdx.y * 512;           // 8 k-slices
    const int w = t >> 6, lane = t & 63;
    const int m = lane & 15, q = lane >> 4;
    const int srow = t >> 4, sf = t & 15;      // A staging: 16 rows x 16 float4
    const int bn = t >> 2, bc = t & 3;         // B staging: 64 rows x 4 thr
    ffrag acc = (ffrag){0.f, 0.f, 0.f, 0.f};
    float dacc = 0.f;
    const float* abase = adj + (size_t)(rb * 16 + srow) * NN + k0;
    const unsigned short* bbase = xwT + (size_t)bn * NN + k0;
    for (int kt = 0; kt < 512; kt += 64) {
        {
            const float4 v = *(const float4*)(abase + kt + 4 * sf);
            dacc += v.x + v.y + v.z + v.w;
            *(uint2*)(a_sh + srow * 72 + 4 * sf) = make_uint2(pk2(v.x, v.y), pk2(v.z, v.w));
        }
#pragma unroll
        for (int k = 0; k < 2; ++k) {
            const int c2 = bc + 4 * k;         // bfrag slot 0..7
            *(bfrag*)(b_sh + bn * 72 + c2 * 8) = *(const bfrag*)(bbase + kt + c2 * 8);
        }
        __syncthreads();
#pragma unroll
        for (int ks = 0; ks < 2; ++ks) {
            const bfrag af = *(const bfrag*)(a_sh + m * 72 + ks * 32 + q * 8);
            const bfrag bf = *(const bfrag*)(b_sh + (w * 16 + m) * 72 + ks * 32 + q * 8);
            acc = __builtin_amdgcn_mfma_f32_16x16x32_bf16(af, bf, acc, 0, 0, 0);
        }
        __syncthreads();
    }
    float* op = ypart + (size_t)blockIdx.y * NN * DIM;
#pragma unroll
    for (int r = 0; r < 4; ++r)
        op[(size_t)(rb * 16 + q * 4 + r) * DIM + w * 16 + m] = acc[r];
    dacc += __shfl_down(dacc, 8, 64);
    dacc += __shfl_down(dacc, 4, 64);
    dacc += __shfl_down(dacc, 2, 64);
    dacc += __shfl_down(dacc, 1, 64);
    if (sf == 0) atomicAdd(&dflat[rb * 16 + srow], dacc);
}

// mincut_num partials: S .* (adj @ S), 16-row tiles, grid (256, 8).
__global__ __launch_bounds__(256) void spmmT(const float* __restrict__ adj,
                                             const unsigned short* __restrict__ ST,
                                             const unsigned short* __restrict__ Sb16,
                                             float* __restrict__ nump) {
    __shared__ __align__(16) unsigned short a_sh[16 * 72];
    __shared__ __align__(16) unsigned short s_sh[128 * 72];
    __shared__ float red[4];
    const int t  = threadIdx.x;
    const int rb = blockIdx.x;                 // 0..255
    const int k0 = blockIdx.y * 512;
    const int w = t >> 6, lane = t & 63;
    const int m = lane & 15, q = lane >> 4;
    const int srow = t >> 4, sf = t & 15;      // A staging: 16 rows x 16 float4
    const int sn = t >> 1, sc2 = t & 1;        // S staging: 128 rows x 2 thr
    ffrag acc[2];
    acc[0] = (ffrag){0.f, 0.f, 0.f, 0.f};
    acc[1] = (ffrag){0.f, 0.f, 0.f, 0.f};
    const float* abase = adj + (size_t)(rb * 16 + srow) * NN + k0;
    const unsigned short* sbase = ST + (size_t)sn * NN + k0;
    for (int kt = 0; kt < 512; kt += 64) {
        {
            const float4 v = *(const float4*)(abase + kt + 4 * sf);
            *(uint2*)(a_sh + srow * 72 + 4 * sf) = make_uint2(pk2(v.x, v.y), pk2(v.z, v.w));
        }
#pragma unroll
        for (int k = 0; k < 4; ++k) {
            const int c2 = sc2 + 2 * k;        // bfrag slot 0..7
            *(bfrag*)(s_sh + sn * 72 + c2 * 8) = *(const bfrag*)(sbase + kt + c2 * 8);
        }
        __syncthreads();
#pragma unroll
        for (int ks = 0; ks < 2; ++ks) {
            const bfrag af = *(const bfrag*)(a_sh + m * 72 + ks * 32 + q * 8);
#pragma unroll
            for (int j = 0; j < 2; ++j) {
                const bfrag bf = *(const bfrag*)(s_sh + ((w * 2 + j) * 16 + m) * 72 + ks * 32 + q * 8);
                acc[j] = __builtin_amdgcn_mfma_f32_16x16x32_bf16(af, bf, acc[j], 0, 0, 0);
            }
        }
        __syncthreads();
    }
    float local = 0.f;
#pragma unroll
    for (int j = 0; j < 2; ++j)
#pragma unroll
        for (int r = 0; r < 4; ++r) {
            const int row = rb * 16 + q * 4 + r;
            const int col = (w * 2 + j) * 16 + m;
            local += acc[j][r] * bf2f(Sb16[(size_t)row * 128 + col]);
        }
    local = wsum(local);
    if (lane == 0) red[w] = local;
    __syncthreads();
    if (t == 0) nump[blockIdx.y * 256 + rb] = red[0] + red[1] + red[2] + red[3];
}

// y = sum(8 y_part) + xw + conv_b ; per-channel sum/sumsq
__global__ __launch_bounds__(256) void bnstat(const float* __restrict__ ypart,
                                              const float* __restrict__ xw,
                                              const float* __restrict__ conv_b,
                                              float* __restrict__ Y0,
                                              float* __restrict__ chsum,
                                              float* __restrict__ chsq) {
    __shared__ float ssum[64], ssq[64];
    const int t = threadIdx.x;
    if (t < 64) { ssum[t] = 0.f; ssq[t] = 0.f; }
    __syncthreads();
    const int tid = blockIdx.x * 256 + t;
    const size_t e = (size_t)tid * 4;
    const int c0 = (int)(e & 63);
    float4 v = *(const float4*)(xw + e);
#pragma unroll
    for (int s = 0; s < 8; ++s) {
        const float4 u = *(const float4*)(ypart + (size_t)s * NN * DIM + e);
        v.x += u.x; v.y += u.y; v.z += u.z; v.w += u.w;
    }
    const float4 b = *(const float4*)(conv_b + c0);
    v.x += b.x; v.y += b.y; v.z += b.z; v.w += b.w;
    *(float4*)(Y0 + e) = v;
    atomicAdd(&ssum[c0 + 0], v.x); atomicAdd(&ssum[c0 + 1], v.y);
    atomicAdd(&ssum[c0 + 2], v.z); atomicAdd(&ssum[c0 + 3], v.w);
    atomicAdd(&ssq[c0 + 0], v.x * v.x); atomicAdd(&ssq[c0 + 1], v.y * v.y);
    atomicAdd(&ssq[c0 + 2], v.z * v.z); atomicAdd(&ssq[c0 + 3], v.w * v.w);
    __syncthreads();
    if (t < 64) { atomicAdd(&chsum[t], ssum[t]); atomicAdd(&chsq[t], ssq[t]); }
}

// per-row: BN affine, L2 norm, softmax -> Sb16 + ST (fused transpose) + YnT; den partials
__global__ __launch_bounds__(256) void rowsk(const float* __restrict__ Y0,
                                             const float* __restrict__ bn_g,
                                             const float* __restrict__ bn_b,
                                             const float* __restrict__ chsum,
                                             const float* __restrict__ chsq,
                                             const float* __restrict__ pool_w,
                                             const float* __restrict__ pool_b,
                                             const float* __restrict__ dflat,
                                             unsigned short* __restrict__ YnT,
                                             unsigned short* __restrict__ Sb16,
                                             unsigned short* __restrict__ ST,
                                             float* __restrict__ denp) {
    __shared__ float scale_sh[64], shift_sh[64];
    __shared__ float yn_sh[4][64];
    __shared__ float4 pw4[16 * 104];   // pw4[dq*104+k] = pool_w[4dq..4dq+3][k]
    __shared__ unsigned short sb_sh[4][128];
    __shared__ float denw[4];
    const int t = threadIdx.x;
    if (t < 64) {
        const float mn  = chsum[t] * (1.f / 4096.f);
        const float var = chsq[t] * (1.f / 4096.f) - mn * mn;
        const float sc  = bn_g[t] * rsqrtf(var + 1e-5f);
        scale_sh[t] = sc;
        shift_sh[t] = bn_b[t] - mn * sc;
    }
    for (int idx = t; idx < 16 * KC; idx += 256) {
        const int dq = idx / KC, k = idx - dq * KC;
        pw4[dq * 104 + k] = make_float4(pool_w[(4 * dq + 0) * KC + k],
                                        pool_w[(4 * dq + 1) * KC + k],
                                        pool_w[(4 * dq + 2) * KC + k],
                                        pool_w[(4 * dq + 3) * KC + k]);
    }
    __syncthreads();
    const int w = t >> 6, lane = t & 63;
    const int row = blockIdx.x * 4 + w;
    float v = Y0[(size_t)row * 64 + lane] * scale_sh[lane] + shift_sh[lane];
    const float nrm = fmaxf(sqrtf(wsum(v * v)), 1e-12f);
    const float yn = v / nrm;
    yn_sh[w][lane] = yn;
    const bool v2 = (lane + 64) < KC;
    const int j2 = v2 ? (lane + 64) : 0;     // clamped (finite garbage, masked later)
    float L1 = pool_b[lane];
    float L2 = pool_b[j2];
    __syncthreads();
#pragma unroll
    for (int dq = 0; dq < 16; ++dq) {
        const float4 yv = *(const float4*)&yn_sh[w][4 * dq];
        const float4 w1 = pw4[dq * 104 + lane];
        L1 += yv.x * w1.x + yv.y * w1.y + yv.z * w1.z + yv.w * w1.w;
        const float4 w2 = pw4[dq * 104 + j2];
        L2 += yv.x * w2.x + yv.y * w2.y + yv.z * w2.z + yv.w * w2.w;
    }
    const float mx = wmax(fmaxf(L1, v2 ? L2 : -1e30f));
    const float e1 = expf(L1 - mx);
    const float e2 = v2 ? expf(L2 - mx) : 0.f;
    const float inv = 1.f / wsum(e1 + e2);
    const float s1 = e1 * inv, s2 = e2 * inv;
    const unsigned short b1 = f2bf(s1), b2 = f2bf(s2);
    Sb16[(size_t)row * 128 + lane] = b1;
    Sb16[(size_t)row * 128 + 64 + lane] = b2;   // zero for cols >= 100
    sb_sh[w][lane] = b1;
    sb_sh[w][64 + lane] = b2;
    const float c = wsum(s1 * s1 + s2 * s2);
    if (lane == 0) denw[w] = dflat[row] * c;
    __syncthreads();
    if (t < 64) {
        // YnT: 4 consecutive rows of column d as one 8B store
        ushort4 o;
        o.x = f2bf(yn_sh[0][t]); o.y = f2bf(yn_sh[1][t]);
        o.z = f2bf(yn_sh[2][t]); o.w = f2bf(yn_sh[3][t]);
        *(ushort4*)(YnT + (size_t)t * NN + blockIdx.x * 4) = o;
    } else if (t < 192) {
        // ST: 4 consecutive rows of S column c as one 8B store
        const int c2 = t - 64;
        ushort4 o;
        o.x = sb_sh[0][c2]; o.y = sb_sh[1][c2];
        o.z = sb_sh[2][c2]; o.w = sb_sh[3][c2];
        *(ushort4*)(ST + (size_t)c2 * NN + blockIdx.x * 4) = o;
    } else if (t == 192) {
        denp[blockIdx.x] = denw[0] + denw[1] + denw[2] + denw[3];
    }
}

// gram partials: C[128][192] = ST @ [YnT|ST]^T, 64 k-splits. grid 64.
__global__ __launch_bounds__(256) void gram(const unsigned short* __restrict__ ST,
                                            const unsigned short* __restrict__ YnT,
                                            float* __restrict__ gpart) {
    __shared__ __align__(16) unsigned short a_sh[128 * 72];
    __shared__ __align__(16) unsigned short b_sh[192 * 72];
    const int t = threadIdx.x;
    const int k0 = blockIdx.x * 64;
    const int w = t >> 6, lane = t & 63;
    const int m = lane & 15, q = lane >> 4;
#pragma unroll
    for (int p = 0; p < 4; ++p) {
        const int n = (t >> 3) + 32 * p, c = t & 7;
        *(bfrag*)(a_sh + n * 72 + c * 8) = *(const bfrag*)(ST + (size_t)n * NN + k0 + c * 8);
    }
#pragma unroll
    for (int p = 0; p < 6; ++p) {
        const int n = (t >> 3) + 32 * p, c = t & 7;
        const unsigned short* src = (n < 64) ? (YnT + (size_t)n * NN + k0 + c * 8)
                                             : (ST + (size_t)(n - 64) * NN + k0 + c * 8);
        *(bfrag*)(b_sh + n * 72 + c * 8) = *(const bfrag*)src;
    }
    __syncthreads();
    ffrag acc[2][12];
#pragma unroll
    for (int i = 0; i < 2; ++i)
#pragma unroll
        for (int j = 0; j < 12; ++j) acc[i][j] = (ffrag){0.f, 0.f, 0.f, 0.f};
#pragma unroll
    for (int ks = 0; ks < 2; ++ks) {
        const bfrag af0 = *(const bfrag*)(a_sh + (w * 32 +  0 + m) * 72 + ks * 32 + q * 8);
        const bfrag af1 = *(const bfrag*)(a_sh + (w * 32 + 16 + m) * 72 + ks * 32 + q * 8);
#pragma unroll
        for (int j = 0; j < 12; ++j) {
            const bfrag bf = *(const bfrag*)(b_sh + (j * 16 + m) * 72 + ks * 32 + q * 8);
            acc[0][j] = __builtin_amdgcn_mfma_f32_16x16x32_bf16(af0, bf, acc[0][j], 0, 0, 0);
            acc[1][j] = __builtin_amdgcn_mfma_f32_16x16x32_bf16(af1, bf, acc[1][j], 0, 0, 0);
        }
    }
    float* op = gpart + (size_t)blockIdx.x * 128 * 192;
#pragma unroll
    for (int i = 0; i < 2; ++i)
#pragma unroll
        for (int j = 0; j < 12; ++j)
#pragma unroll
            for (int r = 0; r < 4; ++r)
                op[(size_t)(w * 32 + i * 16 + q * 4 + r) * 192 + j * 16 + m] = acc[i][j][r];
}

// reduce 64 gram slices -> tbuf (tokens) + ss
__global__ __launch_bounds__(256) void gramred(const float* __restrict__ gpart,
                                               const float* __restrict__ cls,
                                               float* __restrict__ tbuf,
                                               float* __restrict__ ss) {
    const int tid = blockIdx.x * 256 + threadIdx.x;
    if (tid < 128 * 192) {
        const int row = tid / 192, col = tid - row * 192;
        float v = 0.f;
        for (int s = 0; s < 64; ++s) v += gpart[(size_t)s * 128 * 192 + tid];
        if (row < KC) {
            if (col < 64) tbuf[(row + 1) * 64 + col] = v;
            else if (col < 164) ss[row * KC + (col - 64)] = v;
        }
    } else if (tid < 128 * 192 + 64) {
        const int c = tid - 128 * 192;
        tbuf[c] = cls[c];
    }
}

// transformer stage A: LN1 + QKV. One token per block, 512 thr, qkv_w staged in LDS,
// 2-way e-split matvec.
__global__ __launch_bounds__(512) void attnA(const float* __restrict__ tbuf,
                                             const float* __restrict__ g1,
                                             const float* __restrict__ b1,
                                             const float* __restrict__ qw,
                                             const float* __restrict__ qb,
                                             float* __restrict__ qkvb, int l) {
    __shared__ float wl[64 * 192];   // 48KB
    __shared__ float hs[64];
    __shared__ float part[2][196];
    const int t = threadIdx.x, tok = blockIdx.x;
    const float* wsrc = qw + (size_t)l * 64 * 192;
#pragma unroll
    for (int p = 0; p < 6; ++p) {
        const int idx = t + 512 * p;   // 3072 float4 total
        ((float4*)wl)[idx] = ((const float4*)wsrc)[idx];
    }
    if (t < 64) {
        const float x = tbuf[tok * 64 + t];
        const float m = wsum(x) * (1.f / 64.f);
        const float var = wsum(x * x) * (1.f / 64.f) - m * m;
        hs[t] = (x - m) * rsqrtf(var + 1e-6f) * g1[l * 64 + t] + b1[l * 64 + t];
    }
    __syncthreads();
    if (t < 384) {
        const int o = t % 192, grp = t / 192;
        float a = 0.f;
#pragma unroll 8
        for (int e = grp * 32; e < grp * 32 + 32; ++e)
            a += hs[e] * wl[e * 192 + o];
        part[grp][o] = a;
    }
    __syncthreads();
    if (t < 192)
        qkvb[tok * 192 + t] = qb[l * 192 + t] + part[0][t] + part[1][t];
}

// transformer stage B: attention + proj + LN2 + MLP, one token per block.
// 512 threads, every phase 4-8 way parallel over the reduce dim + LDS partials.
__global__ __launch_bounds__(512) void attnB(float* __restrict__ tbuf,
                                             const float* __restrict__ qkvb,
                                             const float* __restrict__ pw,
                                             const float* __restrict__ pb,
                                             const float* __restrict__ g2,
                                             const float* __restrict__ b2,
                                             const float* __restrict__ w1,
                                             const float* __restrict__ bb1,
                                             const float* __restrict__ w2,
                                             const float* __restrict__ bb2, int l) {
    __shared__ float big[13332];        // phase1: kv[101][132]; later: weight chunks
    __shared__ float sc[8 * 104];       // scores / probs
    __shared__ float part[8][132];      // cross-group partials
    __shared__ float q_l[64], osh[64], h2sh[64], gsh[256];
    const int t = threadIdx.x, qtok = blockIdx.x;
    float t_old = 0.f;
    if (t < 64) t_old = tbuf[qtok * 64 + t];
    // ---- phase 1: stage K|V rows (132-stride to break bank aliasing) ----
#pragma unroll
    for (int p = 0; p < 7; ++p) {
        const int idx = t + 512 * p;            // 3232 float4 items
        if (idx < 101 * 32) {
            const int k = idx >> 5, c = idx & 31;
            *(float4*)&big[k * 132 + c * 4] = *(const float4*)(qkvb + k * 192 + 64 + c * 4);
        }
    }
    if (t < 16) *(float4*)&q_l[t * 4] = *(const float4*)(qkvb + qtok * 192 + t * 4);
    __syncthreads();
    // ---- scores: 808 (h,k) pairs ----
    const float scale = 0.35355339059327373f;
#pragma unroll
    for (int p = 0; p < 2; ++p) {
        const int idx = t + 512 * p;
        if (idx < 808) {
            const int h = idx / 101, k = idx - h * 101;
            float s = 0.f;
#pragma unroll
            for (int d = 0; d < 8; ++d)
                s += q_l[h * 8 + d] * big[k * 132 + h * 8 + d];
            sc[h * 104 + k] = s * scale;
        }
    }
    __syncthreads();
    // ---- softmax per head: 32-lane half-wave per head (waves 0..3) ----
    if (t < 256) {
        const int w = t >> 6;
        const int h = w * 2 + ((t >> 5) & 1);   // head 0..7
        const int lft = t & 31;
        float v[4];
#pragma unroll
        for (int g = 0; g < 4; ++g) {
            const int k = lft + 32 * g;
            v[g] = (k < 101) ? sc[h * 104 + k] : -1e30f;
        }
        float m = fmaxf(fmaxf(v[0], v[1]), fmaxf(v[2], v[3]));
        m = hmax32(m);
        float s = 0.f;
#pragma unroll
        for (int g = 0; g < 4; ++g) { v[g] = expf(v[g] - m); s += v[g]; }
        s = hsum32(s);
        const float inv = 1.f / s;
#pragma unroll
        for (int g = 0; g < 4; ++g) {
            const int k = lft + 32 * g;
            if (k < 101) sc[h * 104 + k] = v[g] * inv;
        }
    }
    __syncthreads();
    // ---- O = P @ V : 8-way k-split ----
    {
        const int o = t & 63, grp = t >> 6;
        float po = 0.f;
        for (int k = grp; k < 101; k += 8)
            po += sc[(o >> 3) * 104 + k] * big[k * 132 + 64 + o];
        part[grp][o] = po;
    }
    __syncthreads();
    if (t < 64)
        osh[t] = part[0][t] + part[1][t] + part[2][t] + part[3][t]
               + part[4][t] + part[5][t] + part[6][t] + part[7][t];
    __syncthreads();
    // ---- phase 2: proj (16KB into big), 8-way e-split + LN2 ----
#pragma unroll
    for (int p = 0; p < 2; ++p) {
        const int idx = t + 512 * p;            // 1024 float4
        ((float4*)big)[idx] = ((const float4*)(pw + (size_t)l * 4096))[idx];
    }
    __syncthreads();
    {
        const int o = t & 63, grp = t >> 6;
        float pp = 0.f;
#pragma unroll
        for (int e = grp * 8; e < grp * 8 + 8; ++e)
            pp += osh[e] * big[e * 64 + o];
        part[grp][o] = pp;
    }
    __syncthreads();
    float t1 = 0.f;
    if (t < 64) {
        float pr = pb[l * 64 + t];
#pragma unroll
        for (int g = 0; g < 8; ++g) pr += part[g][t];
        t1 = t_old + pr;
        const float m = wsum(t1) * (1.f / 64.f);
        const float var = wsum(t1 * t1) * (1.f / 64.f) - m * m;
        h2sh[t] = (t1 - m) * rsqrtf(var + 1e-6f) * g2[l * 64 + t] + b2[l * 64 + t];
    }
    __syncthreads();
    // ---- phase 3: fc1 in two 128-col chunks, 4-way e-split + GELU ----
    for (int ch = 0; ch < 2; ++ch) {
#pragma unroll
        for (int p = 0; p < 4; ++p) {
            const int idx = t + 512 * p;        // 2048 float4: e=idx/32, c=idx%32
            const int e = idx >> 5, c = idx & 31;
            *(float4*)&big[e * 128 + c * 4] =
                *(const float4*)(w1 + (size_t)l * 16384 + e * 256 + ch * 128 + c * 4);
        }
        __syncthreads();
        {
            const int o = t & 127, grp = t >> 7;    // 4 groups x 16 e
            float pa = 0.f;
#pragma unroll
            for (int e = grp * 16; e < grp * 16 + 16; ++e)
                pa += h2sh[e] * big[e * 128 + o];
            part[grp][o] = pa;
        }
        __syncthreads();
        if (t < 128) {
            float a = bb1[l * 256 + ch * 128 + t]
                    + part[0][t] + part[1][t] + part[2][t] + part[3][t];
            gsh[ch * 128 + t] = 0.5f * a * (1.f + erff(a * 0.70710678118654752f));
        }
        __syncthreads();
    }
    // ---- phase 4: fc2 in two 128-row chunks, 8-way er-split ----
    float a2p = 0.f;
    for (int ch = 0; ch < 2; ++ch) {
#pragma unroll
        for (int p = 0; p < 4; ++p) {
            const int idx = t + 512 * p;        // 2048 float4, contiguous rows
            ((float4*)big)[idx] = ((const float4*)(w2 + (size_t)l * 16384 + ch * 8192))[idx];
        }
        __syncthreads();
        {
            const int o = t & 63, grp = t >> 6; // 8 groups x 16 er
#pragma unroll
            for (int er = grp * 16; er < grp * 16 + 16; ++er)
                a2p += gsh[ch * 128 + er] * big[er * 64 + o];
        }
        __syncthreads();
    }
    {
        const int o = t & 63, grp = t >> 6;
        part[grp][o] = a2p;
    }
    __syncthreads();
    if (t < 64) {
        float a2 = bb2[l * 64 + t];
#pragma unroll
        for (int g = 0; g < 8; ++g) a2 += part[g][t];
        tbuf[qtok * 64 + t] = t1 + a2;
    }
}

__global__ __launch_bounds__(256) void finalk(const float* __restrict__ tbuf,
                                              const float* __restrict__ ng,
                                              const float* __restrict__ nb,
                                              const float* __restrict__ hw,
                                              const float* __restrict__ hb,
                                              const float* __restrict__ ss,
                                              const float* __restrict__ denp,
                                              const float* __restrict__ nump,
                                              float* __restrict__ out) {
    __shared__ float f0[64];
    __shared__ float red[256];
    __shared__ float fro_sh, den_sh, num_sh;
    const int t = threadIdx.x;
    if (t < 64) {
        const float x = tbuf[t];
        const float m = wsum(x) * (1.f / 64.f);
        const float var = wsum(x * x) * (1.f / 64.f) - m * m;
        f0[t] = (x - m) * rsqrtf(var + 1e-6f) * ng[t] + nb[t];
    }
    red[t] = denp[t] + denp[t + 256] + denp[t + 512] + denp[t + 768];
    __syncthreads();
    for (int s = 128; s > 0; s >>= 1) { if (t < s) red[t] += red[t + s]; __syncthreads(); }
    if (t == 0) den_sh = red[0];
    __syncthreads();
    {
        float nsum = 0.f;
#pragma unroll
        for (int i = 0; i < 8; ++i) nsum += nump[t + 256 * i];
        red[t] = nsum;
    }
    __syncthreads();
    for (int s = 128; s > 0; s >>= 1) { if (t < s) red[t] += red[t + s]; __syncthreads(); }
    if (t == 0) num_sh = red[0];
    __syncthreads();
    if (t < 2) {
        float a = hb[t];
        for (int d = 0; d < 64; ++d) a += f0[d] * hw[d * 2 + t];
        out[t] = a;
    }
    if (t == 2) out[2] = -(num_sh / den_sh);
    float s1 = 0.f;
    for (int idx = t; idx < KC * KC; idx += 256) { const float v = ss[idx]; s1 += v * v; }
    __syncthreads();
    red[t] = s1;
    __syncthreads();
    for (int s = 128; s > 0; s >>= 1) { if (t < s) red[t] += red[t + s]; __syncthreads(); }
    if (t == 0) fro_sh = sqrtf(red[0]);
    __syncthreads();
    const float inv = 1.f / fro_sh;
    float s2 = 0.f;
    for (int idx = t; idx < KC * KC; idx += 256) {
        float v = ss[idx] * inv;
        if (idx % 101 == 0) v -= 0.1f;   // diag: I/||I||_F = I/10
        s2 += v * v;
    }
    __syncthreads();
    red[t] = s2;
    __syncthreads();
    for (int s = 128; s > 0; s >>= 1) { if (t < s) red[t] += red[t + s]; __syncthreads(); }
    if (t == 0) out[3] = sqrtf(red[0]);
}

extern "C" void kernel_launch(void* const* d_in, const int* in_sizes, int n_in,
                              void* d_out, int out_size, void* d_ws, size_t ws_size,
                              hipStream_t stream) {
    (void)in_sizes; (void)n_in; (void)out_size; (void)ws_size;
    const float* x      = (const float*)d_in[0];
    const float* adj    = (const float*)d_in[1];
    const float* conv_w = (const float*)d_in[2];
    const float* conv_b = (const float*)d_in[3];
    const float* bn_g   = (const float*)d_in[4];
    const float* bn_b   = (const float*)d_in[5];
    const float* pool_w = (const float*)d_in[6];
    const float* pool_b = (const float*)d_in[7];
    const float* cls    = (const float*)d_in[8];
    const float* ln1_g  = (const float*)d_in[9];
    const float* ln1_b  = (const float*)d_in[10];
    const float* qkv_w  = (const float*)d_in[11];
    const float* qkv_b  = (const float*)d_in[12];
    const float* proj_w = (const float*)d_in[13];
    const float* proj_b = (const float*)d_in[14];
    const float* ln2_g  = (const float*)d_in[15];
    const float* ln2_b  = (const float*)d_in[16];
    const float* fc1_w  = (const float*)d_in[17];
    const float* fc1_b  = (const float*)d_in[18];
    const float* fc2_w  = (const float*)d_in[19];
    const float* fc2_b  = (const float*)d_in[20];
    const float* norm_g = (const float*)d_in[21];
    const float* norm_b = (const float*)d_in[22];
    const float* head_w = (const float*)d_in[23];
    const float* head_b = (const float*)d_in[24];
    float* ws  = (float*)d_ws;
    float* out = (float*)d_out;
    unsigned short* Sb16  = (unsigned short*)(ws + OFF_SB16);
    unsigned short* STb16 = (unsigned short*)(ws + OFF_STB16);
    unsigned short* YnT16 = (unsigned short*)(ws + OFF_YNT16);
    unsigned short* xwT16 = (unsigned short*)(ws + OFF_XWT16);

    // xw = x @ conv_w (fused zero-init of accumulator region)
    xwk<<<256, 256, 0, stream>>>(x, conv_w, ws + OFF_XW, xwT16, ws);
    // y_part = adj @ xw via bf16 MFMA (+ dflat row sums)
    gemmA<<<dim3(256, 8), 256, 0, stream>>>(adj, xwT16, ws + OFF_YPART, ws + OFF_DFLAT);
    bnstat<<<256, 256, 0, stream>>>(ws + OFF_YPART, ws + OFF_XW, conv_b,
                                    ws + OFF_Y0, ws + OFF_CHSUM, ws + OFF_CHSQ);
    rowsk<<<1024, 256, 0, stream>>>(ws + OFF_Y0, bn_g, bn_b, ws + OFF_CHSUM, ws + OFF_CHSQ,
                                    pool_w, pool_b, ws + OFF_DFLAT,
                                    YnT16, Sb16, STb16, ws + OFF_DENP);
    spmmT<<<dim3(256, 8), 256, 0, stream>>>(adj, STb16, Sb16, ws + OFF_NUMP);
    gram<<<64, 256, 0, stream>>>(STb16, YnT16, ws + OFF_GPART);
    gramred<<<97, 256, 0, stream>>>(ws + OFF_GPART, cls, ws + OFF_TBUF, ws + OFF_SS);
    for (int l = 0; l < LL; ++l) {
        attnA<<<101, 512, 0, stream>>>(ws + OFF_TBUF, ln1_g, ln1_b, qkv_w, qkv_b, ws + OFF_QKV, l);
        attnB<<<101, 512, 0, stream>>>(ws + OFF_TBUF, ws + OFF_QKV, proj_w, proj_b,
                                       ln2_g, ln2_b, fc1_w, fc1_b, fc2_w, fc2_b, l);
    }
    finalk<<<1, 256, 0, stream>>>(ws + OFF_TBUF, norm_g, norm_b, head_w, head_b,
                                  ws + OFF_SS, ws + OFF_DENP, ws + OFF_NUMP, out);
}

// Round 11
// 281.914 us; speedup vs baseline: 1.0352x; 1.0352x over previous
//
#include <hip/hip_runtime.h>
#include <hip/hip_bf16.h>
#include <math.h>

#define NN   4096
#define FEAT 512
#define DIM  64
#define KC   100
#define LL   3

// ---- workspace layout (float offsets). Total ~20MB.
#define OFF_DFLAT   0                          // [4096] adj row sums (atomic)
#define OFF_CHSUM   4096                       // [64]
#define OFF_CHSQ    4160                       // [64]
#define ZERO_FLOATS 4224                       // zeroed by xwk blocks 0..16
#define OFF_XW      4224                       // [4096*64] fp32
#define OFF_YPART   (OFF_XW + NN*DIM)          // 8 slices fp32
#define OFF_GPART   (OFF_YPART + 8*NN*DIM)     // [64*128*192]
#define OFF_Y0      (OFF_GPART + 64*128*192)   // [4096*64]
#define OFF_TBUF    (OFF_Y0 + NN*DIM)          // [101*64]
#define OFF_QKV     (OFF_TBUF + 101*DIM)       // [101*192]
#define OFF_SS      (OFF_QKV + 101*192)        // [100*100]
#define OFF_DENP    (OFF_SS + KC*KC)           // [1024]
#define OFF_NUMP    (OFF_DENP + 1024)          // [1024]
#define OFF_SB16    (OFF_NUMP + 1024)          // [4096*128] bf16
#define OFF_STB16   (OFF_SB16 + NN*128/2)      // [128*4096] bf16
#define OFF_YNT16   (OFF_STB16 + NN*128/2)     // [64*4096] bf16
#define OFF_XWT16   (OFF_YNT16 + NN*DIM/2)     // [64*4096] bf16

typedef __attribute__((ext_vector_type(8))) short bfrag;   // 8 bf16 (4 VGPRs)
typedef __attribute__((ext_vector_type(4))) float ffrag;   // 4 fp32 acc

__device__ __forceinline__ unsigned short f2bf(float f) {
    union { float f; unsigned u; } v; v.f = f;
    return (unsigned short)((v.u + 0x7FFFu + ((v.u >> 16) & 1u)) >> 16);
}
__device__ __forceinline__ float bf2f(unsigned short u) {
    union { unsigned u; float f; } v; v.u = (unsigned)u << 16; return v.f;
}
__device__ __forceinline__ unsigned int pk2(float a, float b) {
    __hip_bfloat162 h = __float22bfloat162_rn(make_float2(a, b));
    return *(unsigned int*)&h;
}

__device__ __forceinline__ float wsum(float v) {
#pragma unroll
    for (int o = 32; o > 0; o >>= 1) v += __shfl_xor(v, o, 64);
    return v;
}
__device__ __forceinline__ float wmax(float v) {
#pragma unroll
    for (int o = 32; o > 0; o >>= 1) v = fmaxf(v, __shfl_xor(v, o, 64));
    return v;
}
__device__ __forceinline__ float hsum32(float v) {
#pragma unroll
    for (int o = 16; o > 0; o >>= 1) v += __shfl_xor(v, o, 64);
    return v;
}
__device__ __forceinline__ float hmax32(float v) {
#pragma unroll
    for (int o = 16; o > 0; o >>= 1) v = fmaxf(v, __shfl_xor(v, o, 64));
    return v;
}

// xw = x @ conv_w (fp32, K=512 full) -> xw fp32 + xwT bf16. grid 256 x 16 rows.
// Also zero-inits ws[0..ZERO_FLOATS) from blocks 0..16.
__global__ __launch_bounds__(256) void xwk(const float* __restrict__ x,
                                           const float* __restrict__ B,
                                           float* __restrict__ xw,
                                           unsigned short* __restrict__ xwT,
                                           float* __restrict__ zws) {
    __shared__ float a_sh[16 * 68];
    __shared__ float b_sh[64 * 68];
    __shared__ unsigned short tl[64 * 17];
    const int t = threadIdx.x, rb = blockIdx.x;
    if (rb < 17) {
        const int zi = rb * 256 + t;
        if (zi < ZERO_FLOATS) zws[zi] = 0.f;
    }
    const int r = t >> 4, cg = (t & 15) * 4;
    float4 acc = make_float4(0.f, 0.f, 0.f, 0.f);
    for (int kt = 0; kt < FEAT; kt += 64) {
        *(float4*)&a_sh[(t >> 4) * 68 + (t & 15) * 4] =
            *(const float4*)(x + (size_t)(rb * 16 + (t >> 4)) * FEAT + kt + (t & 15) * 4);
#pragma unroll
        for (int p = 0; p < 4; ++p) {
            const int idx = t + 256 * p;
            const int kr = idx >> 4, c4 = (idx & 15) * 4;
            *(float4*)&b_sh[kr * 68 + c4] = *(const float4*)(B + (size_t)(kt + kr) * DIM + c4);
        }
        __syncthreads();
#pragma unroll 8
        for (int k = 0; k < 64; ++k) {
            const float av = a_sh[r * 68 + k];
            const float4 bv = *(float4*)&b_sh[k * 68 + cg];
            acc.x += av * bv.x; acc.y += av * bv.y;
            acc.z += av * bv.z; acc.w += av * bv.w;
        }
        __syncthreads();
    }
    *(float4*)&xw[(size_t)(rb * 16 + r) * DIM + cg] = acc;
    tl[(cg + 0) * 17 + r] = f2bf(acc.x);
    tl[(cg + 1) * 17 + r] = f2bf(acc.y);
    tl[(cg + 2) * 17 + r] = f2bf(acc.z);
    tl[(cg + 3) * 17 + r] = f2bf(acc.w);
    __syncthreads();
    const int d = t >> 2, c = (t & 3) * 4;
    ushort4 o;
    o.x = tl[d * 17 + c + 0]; o.y = tl[d * 17 + c + 1];
    o.z = tl[d * 17 + c + 2]; o.w = tl[d * 17 + c + 3];
    *(ushort4*)(xwT + (size_t)d * NN + rb * 16 + c) = o;
}

// ypart[ksl] = adj_bf16 @ xwT^T, 32-row tiles, grid (128, 8).
__global__ __launch_bounds__(256) void gemmA(const float* __restrict__ adj,
                                             const unsigned short* __restrict__ xwT,
                                             float* __restrict__ ypart,
                                             float* __restrict__ dflat) {
    __shared__ __align__(16) unsigned short a_sh[32 * 72];
    __shared__ __align__(16) unsigned short b_sh[64 * 72];
    const int t  = threadIdx.x;
    const int rb = blockIdx.x;                 // 0..127
    const int k0 = blockIdx.y * 512;           // 8 k-slices
    const int w = t >> 6, lane = t & 63;
    const int m = lane & 15, q = lane >> 4;
    const int ih = w & 1, jh = w >> 1;         // row-half, col-half
    const int srow = t >> 3, sq = t & 7;       // A staging: 32 rows x 8 thr
    const int bn = t >> 2, bc = t & 3;         // B staging: 64 rows x 4 thr
    ffrag acc[2];
    acc[0] = (ffrag){0.f, 0.f, 0.f, 0.f};
    acc[1] = (ffrag){0.f, 0.f, 0.f, 0.f};
    float dacc = 0.f;
    const float* abase = adj + (size_t)(rb * 32 + srow) * NN + k0;
    const unsigned short* bbase = xwT + (size_t)bn * NN + k0;
    for (int kt = 0; kt < 512; kt += 64) {
#pragma unroll
        for (int k = 0; k < 2; ++k) {
            const int p = sq + 8 * k;          // float4 slot 0..15
            const float4 v = *(const float4*)(abase + kt + 4 * p);
            dacc += v.x + v.y + v.z + v.w;
            *(uint2*)(a_sh + srow * 72 + 4 * p) = make_uint2(pk2(v.x, v.y), pk2(v.z, v.w));
        }
#pragma unroll
        for (int k = 0; k < 2; ++k) {
            const int c2 = bc + 4 * k;         // bfrag slot 0..7
            *(bfrag*)(b_sh + bn * 72 + c2 * 8) = *(const bfrag*)(bbase + kt + c2 * 8);
        }
        __syncthreads();
#pragma unroll
        for (int ks = 0; ks < 2; ++ks) {
            const bfrag af = *(const bfrag*)(a_sh + (ih * 16 + m) * 72 + ks * 32 + q * 8);
#pragma unroll
            for (int jj = 0; jj < 2; ++jj) {
                const bfrag bf = *(const bfrag*)(b_sh + ((jh * 2 + jj) * 16 + m) * 72 + ks * 32 + q * 8);
                acc[jj] = __builtin_amdgcn_mfma_f32_16x16x32_bf16(af, bf, acc[jj], 0, 0, 0);
            }
        }
        __syncthreads();
    }
    float* op = ypart + (size_t)blockIdx.y * NN * DIM;
#pragma unroll
    for (int jj = 0; jj < 2; ++jj)
#pragma unroll
        for (int r = 0; r < 4; ++r)
            op[(size_t)(rb * 32 + ih * 16 + q * 4 + r) * DIM + jh * 32 + jj * 16 + m] = acc[jj][r];
    dacc += __shfl_down(dacc, 1, 64);
    dacc += __shfl_down(dacc, 2, 64);
    dacc += __shfl_down(dacc, 4, 64);
    if (sq == 0) atomicAdd(&dflat[rb * 32 + srow], dacc);
}

// mincut_num partials: S .* (adj @ S), 32-row tiles, grid (128, 8).
__global__ __launch_bounds__(256) void spmmT(const float* __restrict__ adj,
                                             const unsigned short* __restrict__ ST,
                                             const unsigned short* __restrict__ Sb16,
                                             float* __restrict__ nump) {
    __shared__ __align__(16) unsigned short a_sh[32 * 72];
    __shared__ __align__(16) unsigned short s_sh[128 * 72];
    __shared__ float red[4];
    const int t  = threadIdx.x;
    const int rb = blockIdx.x;                 // 0..127
    const int k0 = blockIdx.y * 512;
    const int w = t >> 6, lane = t & 63;
    const int m = lane & 15, q = lane >> 4;
    const int rh = w & 1, ch = w >> 1;         // row-half, col-half (64 cols)
    const int srow = t >> 3, sq = t & 7;
    const int sn = t >> 1, sc2 = t & 1;
    ffrag acc[4];
#pragma unroll
    for (int j = 0; j < 4; ++j) acc[j] = (ffrag){0.f, 0.f, 0.f, 0.f};
    const float* abase = adj + (size_t)(rb * 32 + srow) * NN + k0;
    const unsigned short* sbase = ST + (size_t)sn * NN + k0;
    for (int kt = 0; kt < 512; kt += 64) {
#pragma unroll
        for (int k = 0; k < 2; ++k) {
            const int p = sq + 8 * k;
            const float4 v = *(const float4*)(abase + kt + 4 * p);
            *(uint2*)(a_sh + srow * 72 + 4 * p) = make_uint2(pk2(v.x, v.y), pk2(v.z, v.w));
        }
#pragma unroll
        for (int k = 0; k < 4; ++k) {
            const int c2 = sc2 + 2 * k;        // bfrag slot 0..7
            *(bfrag*)(s_sh + sn * 72 + c2 * 8) = *(const bfrag*)(sbase + kt + c2 * 8);
        }
        __syncthreads();
#pragma unroll
        for (int ks = 0; ks < 2; ++ks) {
            const bfrag af = *(const bfrag*)(a_sh + (rh * 16 + m) * 72 + ks * 32 + q * 8);
#pragma unroll
            for (int j = 0; j < 4; ++j) {
                const bfrag bf = *(const bfrag*)(s_sh + ((ch * 4 + j) * 16 + m) * 72 + ks * 32 + q * 8);
                acc[j] = __builtin_amdgcn_mfma_f32_16x16x32_bf16(af, bf, acc[j], 0, 0, 0);
            }
        }
        __syncthreads();
    }
    float local = 0.f;
#pragma unroll
    for (int j = 0; j < 4; ++j)
#pragma unroll
        for (int r = 0; r < 4; ++r) {
            const int row = rb * 32 + rh * 16 + q * 4 + r;
            const int col = ch * 64 + j * 16 + m;
            local += acc[j][r] * bf2f(Sb16[(size_t)row * 128 + col]);
        }
    local = wsum(local);
    if (lane == 0) red[w] = local;
    __syncthreads();
    if (t == 0) nump[blockIdx.y * 128 + blockIdx.x] = red[0] + red[1] + red[2] + red[3];
}

// y = sum(8 y_part) + xw + conv_b ; per-channel sum/sumsq
__global__ __launch_bounds__(256) void bnstat(const float* __restrict__ ypart,
                                              const float* __restrict__ xw,
                                              const float* __restrict__ conv_b,
                                              float* __restrict__ Y0,
                                              float* __restrict__ chsum,
                                              float* __restrict__ chsq) {
    __shared__ float ssum[64], ssq[64];
    const int t = threadIdx.x;
    if (t < 64) { ssum[t] = 0.f; ssq[t] = 0.f; }
    __syncthreads();
    const int tid = blockIdx.x * 256 + t;
    const size_t e = (size_t)tid * 4;
    const int c0 = (int)(e & 63);
    float4 v = *(const float4*)(xw + e);
#pragma unroll
    for (int s = 0; s < 8; ++s) {
        const float4 u = *(const float4*)(ypart + (size_t)s * NN * DIM + e);
        v.x += u.x; v.y += u.y; v.z += u.z; v.w += u.w;
    }
    const float4 b = *(const float4*)(conv_b + c0);
    v.x += b.x; v.y += b.y; v.z += b.z; v.w += b.w;
    *(float4*)(Y0 + e) = v;
    atomicAdd(&ssum[c0 + 0], v.x); atomicAdd(&ssum[c0 + 1], v.y);
    atomicAdd(&ssum[c0 + 2], v.z); atomicAdd(&ssum[c0 + 3], v.w);
    atomicAdd(&ssq[c0 + 0], v.x * v.x); atomicAdd(&ssq[c0 + 1], v.y * v.y);
    atomicAdd(&ssq[c0 + 2], v.z * v.z); atomicAdd(&ssq[c0 + 3], v.w * v.w);
    __syncthreads();
    if (t < 64) { atomicAdd(&chsum[t], ssum[t]); atomicAdd(&chsq[t], ssq[t]); }
}

// per-row: BN affine, L2 norm, softmax -> Sb16 + ST (fused transpose) + YnT; den partials
__global__ __launch_bounds__(256) void rowsk(const float* __restrict__ Y0,
                                             const float* __restrict__ bn_g,
                                             const float* __restrict__ bn_b,
                                             const float* __restrict__ chsum,
                                             const float* __restrict__ chsq,
                                             const float* __restrict__ pool_w,
                                             const float* __restrict__ pool_b,
                                             const float* __restrict__ dflat,
                                             unsigned short* __restrict__ YnT,
                                             unsigned short* __restrict__ Sb16,
                                             unsigned short* __restrict__ ST,
                                             float* __restrict__ denp) {
    __shared__ float scale_sh[64], shift_sh[64];
    __shared__ float yn_sh[4][64];
    __shared__ float4 pw4[16 * 104];   // pw4[dq*104+k] = pool_w[4dq..4dq+3][k]
    __shared__ unsigned short sb_sh[4][128];
    __shared__ float denw[4];
    const int t = threadIdx.x;
    if (t < 64) {
        const float mn  = chsum[t] * (1.f / 4096.f);
        const float var = chsq[t] * (1.f / 4096.f) - mn * mn;
        const float sc  = bn_g[t] * rsqrtf(var + 1e-5f);
        scale_sh[t] = sc;
        shift_sh[t] = bn_b[t] - mn * sc;
    }
    for (int idx = t; idx < 16 * KC; idx += 256) {
        const int dq = idx / KC, k = idx - dq * KC;
        pw4[dq * 104 + k] = make_float4(pool_w[(4 * dq + 0) * KC + k],
                                        pool_w[(4 * dq + 1) * KC + k],
                                        pool_w[(4 * dq + 2) * KC + k],
                                        pool_w[(4 * dq + 3) * KC + k]);
    }
    __syncthreads();
    const int w = t >> 6, lane = t & 63;
    const int row = blockIdx.x * 4 + w;
    float v = Y0[(size_t)row * 64 + lane] * scale_sh[lane] + shift_sh[lane];
    const float nrm = fmaxf(sqrtf(wsum(v * v)), 1e-12f);
    const float yn = v / nrm;
    yn_sh[w][lane] = yn;
    const bool v2 = (lane + 64) < KC;
    const int j2 = v2 ? (lane + 64) : 0;     // clamped (finite garbage, masked later)
    float L1 = pool_b[lane];
    float L2 = pool_b[j2];
    __syncthreads();
#pragma unroll
    for (int dq = 0; dq < 16; ++dq) {
        const float4 yv = *(const float4*)&yn_sh[w][4 * dq];
        const float4 w1 = pw4[dq * 104 + lane];
        L1 += yv.x * w1.x + yv.y * w1.y + yv.z * w1.z + yv.w * w1.w;
        const float4 w2 = pw4[dq * 104 + j2];
        L2 += yv.x * w2.x + yv.y * w2.y + yv.z * w2.z + yv.w * w2.w;
    }
    const float mx = wmax(fmaxf(L1, v2 ? L2 : -1e30f));
    const float e1 = expf(L1 - mx);
    const float e2 = v2 ? expf(L2 - mx) : 0.f;
    const float inv = 1.f / wsum(e1 + e2);
    const float s1 = e1 * inv, s2 = e2 * inv;
    const unsigned short b1 = f2bf(s1), b2 = f2bf(s2);
    Sb16[(size_t)row * 128 + lane] = b1;
    Sb16[(size_t)row * 128 + 64 + lane] = b2;   // zero for cols >= 100
    sb_sh[w][lane] = b1;
    sb_sh[w][64 + lane] = b2;
    const float c = wsum(s1 * s1 + s2 * s2);
    if (lane == 0) denw[w] = dflat[row] * c;
    __syncthreads();
    if (t < 64) {
        // YnT: 4 consecutive rows of column d as one 8B store
        ushort4 o;
        o.x = f2bf(yn_sh[0][t]); o.y = f2bf(yn_sh[1][t]);
        o.z = f2bf(yn_sh[2][t]); o.w = f2bf(yn_sh[3][t]);
        *(ushort4*)(YnT + (size_t)t * NN + blockIdx.x * 4) = o;
    } else if (t < 192) {
        // ST: 4 consecutive rows of S column c as one 8B store
        const int c2 = t - 64;
        ushort4 o;
        o.x = sb_sh[0][c2]; o.y = sb_sh[1][c2];
        o.z = sb_sh[2][c2]; o.w = sb_sh[3][c2];
        *(ushort4*)(ST + (size_t)c2 * NN + blockIdx.x * 4) = o;
    } else if (t == 192) {
        denp[blockIdx.x] = denw[0] + denw[1] + denw[2] + denw[3];
    }
}

// gram partials: C[128][192] = ST @ [YnT|ST]^T, 64 k-splits. grid 64.
__global__ __launch_bounds__(256) void gram(const unsigned short* __restrict__ ST,
                                            const unsigned short* __restrict__ YnT,
                                            float* __restrict__ gpart) {
    __shared__ __align__(16) unsigned short a_sh[128 * 72];
    __shared__ __align__(16) unsigned short b_sh[192 * 72];
    const int t = threadIdx.x;
    const int k0 = blockIdx.x * 64;
    const int w = t >> 6, lane = t & 63;
    const int m = lane & 15, q = lane >> 4;
#pragma unroll
    for (int p = 0; p < 4; ++p) {
        const int n = (t >> 3) + 32 * p, c = t & 7;
        *(bfrag*)(a_sh + n * 72 + c * 8) = *(const bfrag*)(ST + (size_t)n * NN + k0 + c * 8);
    }
#pragma unroll
    for (int p = 0; p < 6; ++p) {
        const int n = (t >> 3) + 32 * p, c = t & 7;
        const unsigned short* src = (n < 64) ? (YnT + (size_t)n * NN + k0 + c * 8)
                                             : (ST + (size_t)(n - 64) * NN + k0 + c * 8);
        *(bfrag*)(b_sh + n * 72 + c * 8) = *(const bfrag*)src;
    }
    __syncthreads();
    ffrag acc[2][12];
#pragma unroll
    for (int i = 0; i < 2; ++i)
#pragma unroll
        for (int j = 0; j < 12; ++j) acc[i][j] = (ffrag){0.f, 0.f, 0.f, 0.f};
#pragma unroll
    for (int ks = 0; ks < 2; ++ks) {
        const bfrag af0 = *(const bfrag*)(a_sh + (w * 32 +  0 + m) * 72 + ks * 32 + q * 8);
        const bfrag af1 = *(const bfrag*)(a_sh + (w * 32 + 16 + m) * 72 + ks * 32 + q * 8);
#pragma unroll
        for (int j = 0; j < 12; ++j) {
            const bfrag bf = *(const bfrag*)(b_sh + (j * 16 + m) * 72 + ks * 32 + q * 8);
            acc[0][j] = __builtin_amdgcn_mfma_f32_16x16x32_bf16(af0, bf, acc[0][j], 0, 0, 0);
            acc[1][j] = __builtin_amdgcn_mfma_f32_16x16x32_bf16(af1, bf, acc[1][j], 0, 0, 0);
        }
    }
    float* op = gpart + (size_t)blockIdx.x * 128 * 192;
#pragma unroll
    for (int i = 0; i < 2; ++i)
#pragma unroll
        for (int j = 0; j < 12; ++j)
#pragma unroll
            for (int r = 0; r < 4; ++r)
                op[(size_t)(w * 32 + i * 16 + q * 4 + r) * 192 + j * 16 + m] = acc[i][j][r];
}

// reduce 64 gram slices -> tbuf (tokens) + ss
__global__ __launch_bounds__(256) void gramred(const float* __restrict__ gpart,
                                               const float* __restrict__ cls,
                                               float* __restrict__ tbuf,
                                               float* __restrict__ ss) {
    const int tid = blockIdx.x * 256 + threadIdx.x;
    if (tid < 128 * 192) {
        const int row = tid / 192, col = tid - row * 192;
        float v = 0.f;
        for (int s = 0; s < 64; ++s) v += gpart[(size_t)s * 128 * 192 + tid];
        if (row < KC) {
            if (col < 64) tbuf[(row + 1) * 64 + col] = v;
            else if (col < 164) ss[row * KC + (col - 64)] = v;
        }
    } else if (tid < 128 * 192 + 64) {
        const int c = tid - 128 * 192;
        tbuf[c] = cls[c];
    }
}

// transformer stage A: LN1 + QKV (layer 0 only). One token per block, 512 thr.
__global__ __launch_bounds__(512) void attnA(const float* __restrict__ tbuf,
                                             const float* __restrict__ g1,
                                             const float* __restrict__ b1,
                                             const float* __restrict__ qw,
                                             const float* __restrict__ qb,
                                             float* __restrict__ qkvb, int l) {
    __shared__ float wl[64 * 192];   // 48KB
    __shared__ float hs[64];
    __shared__ float part[2][196];
    const int t = threadIdx.x, tok = blockIdx.x;
    const float* wsrc = qw + (size_t)l * 64 * 192;
#pragma unroll
    for (int p = 0; p < 6; ++p) {
        const int idx = t + 512 * p;   // 3072 float4 total
        ((float4*)wl)[idx] = ((const float4*)wsrc)[idx];
    }
    if (t < 64) {
        const float x = tbuf[tok * 64 + t];
        const float m = wsum(x) * (1.f / 64.f);
        const float var = wsum(x * x) * (1.f / 64.f) - m * m;
        hs[t] = (x - m) * rsqrtf(var + 1e-6f) * g1[l * 64 + t] + b1[l * 64 + t];
    }
    __syncthreads();
    if (t < 384) {
        const int o = t % 192, grp = t / 192;
        float a = 0.f;
#pragma unroll 8
        for (int e = grp * 32; e < grp * 32 + 32; ++e)
            a += hs[e] * wl[e * 192 + o];
        part[grp][o] = a;
    }
    __syncthreads();
    if (t < 192)
        qkvb[tok * 192 + t] = qb[l * 192 + t] + part[0][t] + part[1][t];
}

// transformer stage B: attention + proj + LN2 + MLP for one token; for l<2 the
// tail also computes this token's next-layer LN1+QKV (fuses attnA(l+1) away).
__global__ __launch_bounds__(512) void attnB(float* __restrict__ tbuf,
                                             float* __restrict__ qkvb,
                                             const float* __restrict__ pw,
                                             const float* __restrict__ pb,
                                             const float* __restrict__ g2,
                                             const float* __restrict__ b2,
                                             const float* __restrict__ w1,
                                             const float* __restrict__ bb1,
                                             const float* __restrict__ w2,
                                             const float* __restrict__ bb2,
                                             const float* __restrict__ g1,
                                             const float* __restrict__ b1,
                                             const float* __restrict__ qw,
                                             const float* __restrict__ qb,
                                             int l) {
    __shared__ float big[13332];        // phase1: kv[101][132]; later: weight chunks
    __shared__ float sc[8 * 104];       // scores / probs
    __shared__ float part[8][132];      // cross-group partials (flat 1056 floats)
    __shared__ float q_l[64], osh[64], h2sh[64], gsh[256];
    __shared__ float h1sh[64];          // next-layer LN'd token
    float* part2 = (float*)part;        // reuse: [2][192] for next-QKV partials
    const int t = threadIdx.x, qtok = blockIdx.x;
    float t_old = 0.f;
    if (t < 64) t_old = tbuf[qtok * 64 + t];
    // ---- phase 1: stage K|V rows (132-stride to break bank aliasing) ----
#pragma unroll
    for (int p = 0; p < 7; ++p) {
        const int idx = t + 512 * p;            // 3232 float4 items
        if (idx < 101 * 32) {
            const int k = idx >> 5, c = idx & 31;
            *(float4*)&big[k * 132 + c * 4] = *(const float4*)(qkvb + k * 192 + 64 + c * 4);
        }
    }
    if (t < 16) *(float4*)&q_l[t * 4] = *(const float4*)(qkvb + qtok * 192 + t * 4);
    __syncthreads();
    // ---- scores: 808 (h,k) pairs ----
    const float scale = 0.35355339059327373f;
#pragma unroll
    for (int p = 0; p < 2; ++p) {
        const int idx = t + 512 * p;
        if (idx < 808) {
            const int h = idx / 101, k = idx - h * 101;
            float s = 0.f;
#pragma unroll
            for (int d = 0; d < 8; ++d)
                s += q_l[h * 8 + d] * big[k * 132 + h * 8 + d];
            sc[h * 104 + k] = s * scale;
        }
    }
    __syncthreads();
    // ---- softmax per head: 32-lane half-wave per head (waves 0..3) ----
    if (t < 256) {
        const int w = t >> 6;
        const int h = w * 2 + ((t >> 5) & 1);   // head 0..7
        const int lft = t & 31;
        float v[4];
#pragma unroll
        for (int g = 0; g < 4; ++g) {
            const int k = lft + 32 * g;
            v[g] = (k < 101) ? sc[h * 104 + k] : -1e30f;
        }
        float m = fmaxf(fmaxf(v[0], v[1]), fmaxf(v[2], v[3]));
        m = hmax32(m);
        float s = 0.f;
#pragma unroll
        for (int g = 0; g < 4; ++g) { v[g] = expf(v[g] - m); s += v[g]; }
        s = hsum32(s);
        const float inv = 1.f / s;
#pragma unroll
        for (int g = 0; g < 4; ++g) {
            const int k = lft + 32 * g;
            if (k < 101) sc[h * 104 + k] = v[g] * inv;
        }
    }
    __syncthreads();
    // ---- O = P @ V : 8-way k-split ----
    {
        const int o = t & 63, grp = t >> 6;
        float po = 0.f;
        for (int k = grp; k < 101; k += 8)
            po += sc[(o >> 3) * 104 + k] * big[k * 132 + 64 + o];
        part[grp][o] = po;
    }
    __syncthreads();
    if (t < 64)
        osh[t] = part[0][t] + part[1][t] + part[2][t] + part[3][t]
               + part[4][t] + part[5][t] + part[6][t] + part[7][t];
    __syncthreads();
    // ---- phase 2: proj (16KB into big), 8-way e-split + LN2 ----
#pragma unroll
    for (int p = 0; p < 2; ++p) {
        const int idx = t + 512 * p;            // 1024 float4
        ((float4*)big)[idx] = ((const float4*)(pw + (size_t)l * 4096))[idx];
    }
    __syncthreads();
    {
        const int o = t & 63, grp = t >> 6;
        float pp = 0.f;
#pragma unroll
        for (int e = grp * 8; e < grp * 8 + 8; ++e)
            pp += osh[e] * big[e * 64 + o];
        part[grp][o] = pp;
    }
    __syncthreads();
    float t1 = 0.f;
    if (t < 64) {
        float pr = pb[l * 64 + t];
#pragma unroll
        for (int g = 0; g < 8; ++g) pr += part[g][t];
        t1 = t_old + pr;
        const float m = wsum(t1) * (1.f / 64.f);
        const float var = wsum(t1 * t1) * (1.f / 64.f) - m * m;
        h2sh[t] = (t1 - m) * rsqrtf(var + 1e-6f) * g2[l * 64 + t] + b2[l * 64 + t];
    }
    __syncthreads();
    // ---- phase 3: fc1 in two 128-col chunks, 4-way e-split + GELU ----
    for (int ch = 0; ch < 2; ++ch) {
#pragma unroll
        for (int p = 0; p < 4; ++p) {
            const int idx = t + 512 * p;        // 2048 float4: e=idx/32, c=idx%32
            const int e = idx >> 5, c = idx & 31;
            *(float4*)&big[e * 128 + c * 4] =
                *(const float4*)(w1 + (size_t)l * 16384 + e * 256 + ch * 128 + c * 4);
        }
        __syncthreads();
        {
            const int o = t & 127, grp = t >> 7;    // 4 groups x 16 e
            float pa = 0.f;
#pragma unroll
            for (int e = grp * 16; e < grp * 16 + 16; ++e)
                pa += h2sh[e] * big[e * 128 + o];
            part[grp][o] = pa;
        }
        __syncthreads();
        if (t < 128) {
            float a = bb1[l * 256 + ch * 128 + t]
                    + part[0][t] + part[1][t] + part[2][t] + part[3][t];
            gsh[ch * 128 + t] = 0.5f * a * (1.f + erff(a * 0.70710678118654752f));
        }
        __syncthreads();
    }
    // ---- phase 4: fc2 in two 128-row chunks, 8-way er-split ----
    float a2p = 0.f;
    for (int ch = 0; ch < 2; ++ch) {
#pragma unroll
        for (int p = 0; p < 4; ++p) {
            const int idx = t + 512 * p;        // 2048 float4, contiguous rows
            ((float4*)big)[idx] = ((const float4*)(w2 + (size_t)l * 16384 + ch * 8192))[idx];
        }
        __syncthreads();
        {
            const int o = t & 63, grp = t >> 6; // 8 groups x 16 er
#pragma unroll
            for (int er = grp * 16; er < grp * 16 + 16; ++er)
                a2p += gsh[ch * 128 + er] * big[er * 64 + o];
        }
        __syncthreads();
    }
    {
        const int o = t & 63, grp = t >> 6;
        part[grp][o] = a2p;
    }
    __syncthreads();
    if (t < 64) {
        float a2 = bb2[l * 64 + t];
#pragma unroll
        for (int g = 0; g < 8; ++g) a2 += part[g][t];
        const float tn = t1 + a2;
        tbuf[qtok * 64 + t] = tn;
        if (l < 2) {
            const float m = wsum(tn) * (1.f / 64.f);
            const float var = wsum(tn * tn) * (1.f / 64.f) - m * m;
            h1sh[t] = (tn - m) * rsqrtf(var + 1e-6f) * g1[(l + 1) * 64 + t]
                      + b1[(l + 1) * 64 + t];
        }
    }
    if (l < 2) {
        // ---- tail: next-layer QKV for own token (fuses attnA(l+1)) ----
        __syncthreads();
#pragma unroll
        for (int p = 0; p < 6; ++p) {
            const int idx = t + 512 * p;        // 3072 float4 = qkv_w[l+1]
            ((float4*)big)[idx] = ((const float4*)(qw + (size_t)(l + 1) * 12288))[idx];
        }
        __syncthreads();
        if (t < 384) {
            const int o = t % 192, grp = t / 192;
            float a = 0.f;
#pragma unroll 8
            for (int e = grp * 32; e < grp * 32 + 32; ++e)
                a += h1sh[e] * big[e * 192 + o];
            part2[grp * 192 + o] = a;
        }
        __syncthreads();
        if (t < 192)
            qkvb[qtok * 192 + t] = qb[(l + 1) * 192 + t] + part2[t] + part2[192 + t];
    }
}

__global__ __launch_bounds__(256) void finalk(const float* __restrict__ tbuf,
                                              const float* __restrict__ ng,
                                              const float* __restrict__ nb,
                                              const float* __restrict__ hw,
                                              const float* __restrict__ hb,
                                              const float* __restrict__ ss,
                                              const float* __restrict__ denp,
                                              const float* __restrict__ nump,
                                              float* __restrict__ out) {
    __shared__ float f0[64];
    __shared__ float red[256];
    __shared__ float fro_sh, den_sh, num_sh;
    const int t = threadIdx.x;
    if (t < 64) {
        const float x = tbuf[t];
        const float m = wsum(x) * (1.f / 64.f);
        const float var = wsum(x * x) * (1.f / 64.f) - m * m;
        f0[t] = (x - m) * rsqrtf(var + 1e-6f) * ng[t] + nb[t];
    }
    red[t] = denp[t] + denp[t + 256] + denp[t + 512] + denp[t + 768];
    __syncthreads();
    for (int s = 128; s > 0; s >>= 1) { if (t < s) red[t] += red[t + s]; __syncthreads(); }
    if (t == 0) den_sh = red[0];
    __syncthreads();
    red[t] = nump[t] + nump[t + 256] + nump[t + 512] + nump[t + 768];
    __syncthreads();
    for (int s = 128; s > 0; s >>= 1) { if (t < s) red[t] += red[t + s]; __syncthreads(); }
    if (t == 0) num_sh = red[0];
    __syncthreads();
    if (t < 2) {
        float a = hb[t];
        for (int d = 0; d < 64; ++d) a += f0[d] * hw[d * 2 + t];
        out[t] = a;
    }
    if (t == 2) out[2] = -(num_sh / den_sh);
    float s1 = 0.f;
    for (int idx = t; idx < KC * KC; idx += 256) { const float v = ss[idx]; s1 += v * v; }
    __syncthreads();
    red[t] = s1;
    __syncthreads();
    for (int s = 128; s > 0; s >>= 1) { if (t < s) red[t] += red[t + s]; __syncthreads(); }
    if (t == 0) fro_sh = sqrtf(red[0]);
    __syncthreads();
    const float inv = 1.f / fro_sh;
    float s2 = 0.f;
    for (int idx = t; idx < KC * KC; idx += 256) {
        float v = ss[idx] * inv;
        if (idx % 101 == 0) v -= 0.1f;   // diag: I/||I||_F = I/10
        s2 += v * v;
    }
    __syncthreads();
    red[t] = s2;
    __syncthreads();
    for (int s = 128; s > 0; s >>= 1) { if (t < s) red[t] += red[t + s]; __syncthreads(); }
    if (t == 0) out[3] = sqrtf(red[0]);
}

extern "C" void kernel_launch(void* const* d_in, const int* in_sizes, int n_in,
                              void* d_out, int out_size, void* d_ws, size_t ws_size,
                              hipStream_t stream) {
    (void)in_sizes; (void)n_in; (void)out_size; (void)ws_size;
    const float* x      = (const float*)d_in[0];
    const float* adj    = (const float*)d_in[1];
    const float* conv_w = (const float*)d_in[2];
    const float* conv_b = (const float*)d_in[3];
    const float* bn_g   = (const float*)d_in[4];
    const float* bn_b   = (const float*)d_in[5];
    const float* pool_w = (const float*)d_in[6];
    const float* pool_b = (const float*)d_in[7];
    const float* cls    = (const float*)d_in[8];
    const float* ln1_g  = (const float*)d_in[9];
    const float* ln1_b  = (const float*)d_in[10];
    const float* qkv_w  = (const float*)d_in[11];
    const float* qkv_b  = (const float*)d_in[12];
    const float* proj_w = (const float*)d_in[13];
    const float* proj_b = (const float*)d_in[14];
    const float* ln2_g  = (const float*)d_in[15];
    const float* ln2_b  = (const float*)d_in[16];
    const float* fc1_w  = (const float*)d_in[17];
    const float* fc1_b  = (const float*)d_in[18];
    const float* fc2_w  = (const float*)d_in[19];
    const float* fc2_b  = (const float*)d_in[20];
    const float* norm_g = (const float*)d_in[21];
    const float* norm_b = (const float*)d_in[22];
    const float* head_w = (const float*)d_in[23];
    const float* head_b = (const float*)d_in[24];
    float* ws  = (float*)d_ws;
    float* out = (float*)d_out;
    unsigned short* Sb16  = (unsigned short*)(ws + OFF_SB16);
    unsigned short* STb16 = (unsigned short*)(ws + OFF_STB16);
    unsigned short* YnT16 = (unsigned short*)(ws + OFF_YNT16);
    unsigned short* xwT16 = (unsigned short*)(ws + OFF_XWT16);

    // xw = x @ conv_w (fused zero-init of accumulator region)
    xwk<<<256, 256, 0, stream>>>(x, conv_w, ws + OFF_XW, xwT16, ws);
    // y_part = adj @ xw via bf16 MFMA (+ dflat row sums)
    gemmA<<<dim3(128, 8), 256, 0, stream>>>(adj, xwT16, ws + OFF_YPART, ws + OFF_DFLAT);
    bnstat<<<256, 256, 0, stream>>>(ws + OFF_YPART, ws + OFF_XW, conv_b,
                                    ws + OFF_Y0, ws + OFF_CHSUM, ws + OFF_CHSQ);
    rowsk<<<1024, 256, 0, stream>>>(ws + OFF_Y0, bn_g, bn_b, ws + OFF_CHSUM, ws + OFF_CHSQ,
                                    pool_w, pool_b, ws + OFF_DFLAT,
                                    YnT16, Sb16, STb16, ws + OFF_DENP);
    spmmT<<<dim3(128, 8), 256, 0, stream>>>(adj, STb16, Sb16, ws + OFF_NUMP);
    gram<<<64, 256, 0, stream>>>(STb16, YnT16, ws + OFF_GPART);
    gramred<<<97, 256, 0, stream>>>(ws + OFF_GPART, cls, ws + OFF_TBUF, ws + OFF_SS);
    attnA<<<101, 512, 0, stream>>>(ws + OFF_TBUF, ln1_g, ln1_b, qkv_w, qkv_b, ws + OFF_QKV, 0);
    for (int l = 0; l < LL; ++l) {
        attnB<<<101, 512, 0, stream>>>(ws + OFF_TBUF, ws + OFF_QKV, proj_w, proj_b,
                                       ln2_g, ln2_b, fc1_w, fc1_b, fc2_w, fc2_b,
                                       ln1_g, ln1_b, qkv_w, qkv_b, l);
    }
    finalk<<<1, 256, 0, stream>>>(ws + OFF_TBUF, norm_g, norm_b, head_w, head_b,
                                  ws + OFF_SS, ws + OFF_DENP, ws + OFF_NUMP, out);
}